// Round 2
// baseline (562.799 us; speedup 1.0000x reference)
//
#include <hip/hip_runtime.h>
#include <math.h>

// B=128, E=8, D=512, H=2048. 64 (a,e) pairs.
// Pass1: h = gelu(feat[:,a] @ W1[p] + b1[p]) -> bf16 hbuf [pair][H/32][128][32]
// Pass2: out = h @ W2[p] + b2[p]; squared-error accumulate -> partials[512]
// Pass3: reduce -> scalar.
//
// v2 (resubmit; round-1 bench was an infra failure, kernel never ran):
//  - raw s_barrier with lgkm-only drain: vmcnt prefetch survives barriers
//  - LDS double-buffer, ONE barrier per 32-k step (was 2)
//  - A-operand fragments loaded DIRECT from global (feat / hbuf are
//    k-contiguous per lane and L2-resident) -- no lA staging at all
//  - depth-2 register prefetch of W1/W2, float2 W1 loads, nontemporal W hints
//  - s_setprio(1) around MFMA clusters

typedef float floatx4 __attribute__((ext_vector_type(4)));
typedef float floatx2 __attribute__((ext_vector_type(2)));
typedef __bf16 bf16x8 __attribute__((ext_vector_type(8)));
typedef unsigned short ushortx8 __attribute__((ext_vector_type(8)));

__device__ __forceinline__ unsigned short f2bf(float f) {
    unsigned u = __builtin_bit_cast(unsigned, f);
    u += 0x7fffu + ((u >> 16) & 1u);   // RNE
    return (unsigned short)(u >> 16);
}

// Raw barrier: drain LDS ops (cross-wave visibility of ds_writes/reads) but
// leave global loads (vmcnt) in flight. __syncthreads would drain vmcnt(0).
__device__ __forceinline__ void barrier_nd() {
    asm volatile("s_waitcnt lgkmcnt(0)" ::: "memory");
    __builtin_amdgcn_s_barrier();
}

#define LDSTR 40   // LDS row stride in shorts (80 B): conflict-free frag reads

// ---------------------------------------------------------------- pass 1
// 1024 blocks: 64 pairs x 16 n-tiles of 128 over H=2048. 3 blocks/CU.
__global__ __launch_bounds__(256, 3) void k_gemm1(
    const float* __restrict__ feat, const float* __restrict__ W1,
    const float* __restrict__ b1, unsigned short* __restrict__ hbuf)
{
    __shared__ __align__(16) unsigned short lB[2][128 * LDSTR];  // 20.5 KB

    const int bi = blockIdx.x;
    const int xcd = bi & 7, slot = bi >> 3;
    const int pair = xcd * 8 + (slot >> 4);   // all 8 pairs of one 'a' share an XCD
    const int nt   = slot & 15;
    const int a    = pair >> 3;
    const int t = threadIdx.x;
    const int w = t >> 6, l = t & 63;
    const int lr = l & 15, lq = l >> 4;
    const int n_base = nt * 128;
    const int m0 = (w & 1) * 64;
    const int n0 = (w >> 1) * 64;

    // W1 staging: lane covers n = 2l,2l+1; wave covers k-slice [w*8, w*8+8)
    const float* Bp = W1 + (size_t)pair * 512 * 2048 + n_base + 2 * l;
    const int bk0 = w * 8;
    // feat direct A-fragments: row m0+16i+lr, k = kt*32 + lq*8 .. +7 (L2-resident)
    const float* Af = feat + ((size_t)(m0 + lr) * 8 + a) * 512 + lq * 8;

    floatx2 bpf0[8], bpf1[8];

#define G1_LOADB(KT, S)                                                        \
    {                                                                          \
        _Pragma("unroll")                                                      \
        for (int jj = 0; jj < 8; ++jj)                                         \
            S[jj] = __builtin_nontemporal_load(                                \
                (const floatx2*)(Bp + (size_t)((KT) * 32 + bk0 + jj) * 2048)); \
    }

#define G1_STAGEB(S, BUF)                                                      \
    {                                                                          \
        ushortx8 v0, v1;                                                       \
        _Pragma("unroll")                                                      \
        for (int jj = 0; jj < 8; ++jj) {                                       \
            v0[jj] = f2bf(S[jj][0]);                                           \
            v1[jj] = f2bf(S[jj][1]);                                           \
        }                                                                      \
        *(ushortx8*)&lB[BUF][(2 * l) * LDSTR + bk0] = v0;                      \
        *(ushortx8*)&lB[BUF][(2 * l + 1) * LDSTR + bk0] = v1;                  \
    }

    floatx4 acc[4][4];
    const floatx4 zero = {0.f, 0.f, 0.f, 0.f};
    #pragma unroll
    for (int i = 0; i < 4; ++i)
        #pragma unroll
        for (int j = 0; j < 4; ++j) acc[i][j] = zero;

    // prologue: prefetch kt=0,1; stage kt=0
    G1_LOADB(0, bpf0)
    G1_LOADB(1, bpf1)
    G1_STAGEB(bpf0, 0)
    barrier_nd();

// One body = one 32-k step. Reads lB[BUF]; issues W1 loads for KT+2 into SLD
// (consumed at the END of the next body -> ~1.7 bodies of latency cover);
// A-frags loaded in-body from L2 (issued before SLD so their vmcnt wait is
// counted, not a drain); stages SST (KT+1 data) into lB[BUF^1] after MFMA.
#define G1_BODY(KT, BUF, SLD, SST, GLD, GST)                                   \
    {                                                                          \
        bf16x8 bv[4];                                                          \
        _Pragma("unroll")                                                      \
        for (int j = 0; j < 4; ++j)                                            \
            bv[j] = __builtin_bit_cast(bf16x8,                                 \
                *(const ushortx8*)&lB[BUF][(n0 + 16 * j + lr) * LDSTR + lq * 8]); \
        floatx4 a0[4], a1[4];                                                  \
        _Pragma("unroll")                                                      \
        for (int i = 0; i < 4; ++i) {                                          \
            const float* p = Af + (size_t)(65536 * i) + (KT) * 32;             \
            a0[i] = *(const floatx4*)p;                                        \
            a1[i] = *(const floatx4*)(p + 4);                                  \
        }                                                                      \
        if (GLD) G1_LOADB((KT) + 2, SLD)                                       \
        bf16x8 af[4];                                                          \
        _Pragma("unroll")                                                      \
        for (int i = 0; i < 4; ++i) {                                          \
            ushortx8 v;                                                        \
            _Pragma("unroll")                                                  \
            for (int r = 0; r < 4; ++r) {                                      \
                v[r] = f2bf(a0[i][r]);                                         \
                v[4 + r] = f2bf(a1[i][r]);                                     \
            }                                                                  \
            af[i] = __builtin_bit_cast(bf16x8, v);                             \
        }                                                                      \
        __builtin_amdgcn_s_setprio(1);                                         \
        _Pragma("unroll")                                                      \
        for (int i = 0; i < 4; ++i)                                            \
            _Pragma("unroll")                                                  \
            for (int j = 0; j < 4; ++j)                                        \
                acc[i][j] = __builtin_amdgcn_mfma_f32_16x16x32_bf16(           \
                    af[i], bv[j], acc[i][j], 0, 0, 0);                         \
        __builtin_amdgcn_s_setprio(0);                                         \
        if (GST) G1_STAGEB(SST, (BUF) ^ 1)                                     \
        barrier_nd();                                                          \
    }

    #pragma unroll 1
    for (int kt = 0; kt < 16; kt += 2) {
        G1_BODY(kt,     0, bpf0, bpf1, (kt + 2 < 16), 1)
        G1_BODY(kt + 1, 1, bpf1, bpf0, (kt + 3 < 16), (kt + 2 < 16))
    }

    // epilogue: +b1, exact gelu, store bf16 h in [pair][kchunk][row][32] blocks
    #pragma unroll
    for (int j = 0; j < 4; ++j) {
        const int col = n_base + n0 + 16 * j + lr;
        const float bias = b1[pair * 2048 + col];
        const size_t cbase = ((size_t)pair * 64 + (col >> 5)) * 128;
        const int cw = col & 31;
        #pragma unroll
        for (int i = 0; i < 4; ++i)
            #pragma unroll
            for (int r = 0; r < 4; ++r) {
                const int row = m0 + 16 * i + lq * 4 + r;
                float x = acc[i][j][r] + bias;
                float g = 0.5f * x * (1.0f + erff(x * 0.70710678118654752f));
                hbuf[(cbase + row) * 32 + cw] = f2bf(g);
            }
    }
#undef G1_LOADB
#undef G1_STAGEB
#undef G1_BODY
}

// ---------------------------------------------------------------- pass 2
// 512 blocks: 64 pairs x 8 n-tiles of 64 over D=512. 2 blocks/CU (grid-bound).
// hbuf A-fragments loaded DIRECT from global (bf16 already, k-contiguous,
// perfectly coalesced 1 KB/wave-instr, L2-shared across the 8 nt blocks).
__global__ __launch_bounds__(256, 2) void k_gemm2(
    const unsigned short* __restrict__ hbuf, const float* __restrict__ W2,
    const float* __restrict__ b2, const float* __restrict__ tgt,
    float* __restrict__ partials)
{
    __shared__ __align__(16) unsigned short lB[2][64 * LDSTR];   // 10.2 KB
    __shared__ float red[4];

    const int bi = blockIdx.x;
    const int xcd = bi & 7, slot = bi >> 3;
    const int pair = xcd * 8 + (slot >> 3);
    const int nt   = slot & 7;
    const int a    = pair >> 3;
    const int t = threadIdx.x;
    const int w = t >> 6, l = t & 63;
    const int lr = l & 15, lq = l >> 4;
    const int n_base = nt * 64;
    const int m0 = (w & 1) * 64;
    const int n0 = (w >> 1) * 32;

    const float* Bp = W2 + (size_t)pair * 2048 * 512 + n_base + l;
    const int bk0 = w * 8;
    // hbuf chunk kt: [pair][kt][row][32]; frag i: row m0+16i+lr, k-part lq*8
    const unsigned short* Ahp = hbuf + (size_t)pair * 262144
                              + (size_t)(m0 + lr) * 32 + lq * 8;

    float bpf0[8], bpf1[8];
    ushortx8 apf0[4], apf1[4];

#define G2_LOADB(KT, S)                                                        \
    {                                                                          \
        _Pragma("unroll")                                                      \
        for (int jj = 0; jj < 8; ++jj)                                         \
            S[jj] = __builtin_nontemporal_load(                               \
                Bp + (size_t)((KT) * 32 + bk0 + jj) * 512);                    \
    }

#define G2_LOADA(KT, S)                                                        \
    {                                                                          \
        _Pragma("unroll")                                                      \
        for (int i = 0; i < 4; ++i)                                            \
            S[i] = *(const ushortx8*)(Ahp + (size_t)(KT) * 4096 + i * 512);    \
    }

#define G2_STAGEB(S, BUF)                                                      \
    {                                                                          \
        ushortx8 v;                                                            \
        _Pragma("unroll")                                                      \
        for (int jj = 0; jj < 8; ++jj) v[jj] = f2bf(S[jj]);                    \
        *(ushortx8*)&lB[BUF][l * LDSTR + bk0] = v;                             \
    }

    floatx4 acc[4][2];
    const floatx4 zero = {0.f, 0.f, 0.f, 0.f};
    #pragma unroll
    for (int i = 0; i < 4; ++i)
        #pragma unroll
        for (int j = 0; j < 2; ++j) acc[i][j] = zero;

    G2_LOADB(0, bpf0)
    G2_LOADB(1, bpf1)
    G2_LOADA(0, apf0)
    G2_LOADA(1, apf1)
    G2_STAGEB(bpf0, 0)
    barrier_nd();

#define G2_BODY(KT, BUF, SLD, SST, APF, GLD, GST)                              \
    {                                                                          \
        bf16x8 bv[2];                                                          \
        _Pragma("unroll")                                                      \
        for (int j = 0; j < 2; ++j)                                            \
            bv[j] = __builtin_bit_cast(bf16x8,                                 \
                *(const ushortx8*)&lB[BUF][(n0 + 16 * j + lr) * LDSTR + lq * 8]); \
        if (GLD) G2_LOADB((KT) + 2, SLD)                                       \
        __builtin_amdgcn_s_setprio(1);                                         \
        _Pragma("unroll")                                                      \
        for (int i = 0; i < 4; ++i)                                            \
            _Pragma("unroll")                                                  \
            for (int j = 0; j < 2; ++j)                                        \
                acc[i][j] = __builtin_amdgcn_mfma_f32_16x16x32_bf16(           \
                    __builtin_bit_cast(bf16x8, APF[i]), bv[j],                 \
                    acc[i][j], 0, 0, 0);                                       \
        __builtin_amdgcn_s_setprio(0);                                         \
        if (GLD) G2_LOADA((KT) + 2, APF)                                       \
        if (GST) G2_STAGEB(SST, (BUF) ^ 1)                                     \
        barrier_nd();                                                          \
    }

    #pragma unroll 1
    for (int kt = 0; kt < 64; kt += 2) {
        G2_BODY(kt,     0, bpf0, bpf1, apf0, (kt + 2 < 64), 1)
        G2_BODY(kt + 1, 1, bpf1, bpf0, apf1, (kt + 3 < 64), (kt + 2 < 64))
    }

    // epilogue: squared-error accumulation
    float lsum = 0.f;
    #pragma unroll
    for (int j = 0; j < 2; ++j) {
        const int col = n_base + n0 + 16 * j + lr;
        const float bias = b2[pair * 512 + col];
        #pragma unroll
        for (int i = 0; i < 4; ++i)
            #pragma unroll
            for (int r = 0; r < 4; ++r) {
                const int row = m0 + 16 * i + lq * 4 + r;
                float e = acc[i][j][r] + bias - tgt[((size_t)row * 8 + a) * 512 + col];
                lsum += e * e;
            }
    }
    #pragma unroll
    for (int off = 32; off > 0; off >>= 1) lsum += __shfl_down(lsum, off, 64);
    if (l == 0) red[w] = lsum;
    __syncthreads();
    if (t == 0) partials[bi] = red[0] + red[1] + red[2] + red[3];
#undef G2_LOADB
#undef G2_LOADA
#undef G2_STAGEB
#undef G2_BODY
}

// ---------------------------------------------------------------- pass 3
__global__ void k_reduce(const float* __restrict__ partials, float* __restrict__ out)
{
    const int t = threadIdx.x;   // 512 threads
    float v = partials[t];
    #pragma unroll
    for (int off = 32; off > 0; off >>= 1) v += __shfl_down(v, off, 64);
    __shared__ float red[8];
    if ((t & 63) == 0) red[t >> 6] = v;
    __syncthreads();
    if (t == 0) {
        float s = 0.f;
        #pragma unroll
        for (int i = 0; i < 8; ++i) s += red[i];
        out[0] = s * (1.0f / 524288.0f); // /(B*D)/E
    }
}

extern "C" void kernel_launch(void* const* d_in, const int* in_sizes, int n_in,
                              void* d_out, int out_size, void* d_ws, size_t ws_size,
                              hipStream_t stream) {
    const float* feat = (const float*)d_in[0];
    const float* tgt  = (const float*)d_in[1];
    const float* W1   = (const float*)d_in[2];
    const float* b1   = (const float*)d_in[3];
    const float* W2   = (const float*)d_in[4];
    const float* b2   = (const float*)d_in[5];

    unsigned short* hbuf = (unsigned short*)d_ws;                 // 32 MiB bf16 h
    float* partials = (float*)((char*)d_ws + (size_t)33554432);   // 512 floats
    float* out = (float*)d_out;

    k_gemm1<<<dim3(1024), dim3(256), 0, stream>>>(feat, W1, b1, hbuf);
    k_gemm2<<<dim3(512),  dim3(256), 0, stream>>>(hbuf, W2, b2, tgt, partials);
    k_reduce<<<dim3(1),   dim3(512), 0, stream>>>(partials, out);
}